// Round 13
// baseline (47.689 us; speedup 1.0000x reference)
//
#include <hip/hip_runtime.h>

constexpr int BB = 32;
constexpr int NN = 1024;
constexpr int TPB = 512;            // 8 waves
constexpr int WAVES = 8;
constexpr int GH = 256;             // hypotheses per block (4 per lane)
constexpr int MQ = 256;             // m-points per block (quarter of batch)
constexpr int ITERS = MQ / WAVES;   // 32
#define PATCH 14.0f
#define THRSQ 25.0f   // PIXEL_THRESHOLD^2 ; sqrt(x)<=5 <=> x<=25 for correctly-rounded sqrt

// ---------------- Kernel 1: score every hypothesis (R7 champion form) ----------------
// template REPEAT: <1> = real kernel (bit-identical to R7, 19.18us champion);
// <4> = PROFILING PROBE — repeats the m-loop 4x (guards prevent DCE/CSE) so the
// dispatch exceeds the 38us harness fills and surfaces in top-5 WITH counters.
// Probe runs first; its score_part writes are fully overwritten by the real <1>.
template<int REPEAT>
__global__ __launch_bounds__(TPB, 3) void ransac_score_kernel(
    const float* __restrict__ src, const float* __restrict__ tar,
    const float* __restrict__ scores, const float* __restrict__ relScale,
    const float* __restrict__ relInplane, float* __restrict__ score_part)
{
#pragma clang fp contract(off)
    const int bid  = blockIdx.x;
    const int q    = bid & 3;
    const int g    = (bid >> 2) & 3;
    const int b    = bid >> 4;
    const int tid  = threadIdx.x;
    const int wave = tid >> 6;
    const int lane = tid & 63;

    __shared__ float4 pts[MQ];            // (sx,sy,tx,ty)*PATCH for this quarter
    __shared__ float  sc[MQ];             // score, zeroed for invalid points
    __shared__ float  partial[WAVES][GH];

    const float2* src2 = (const float2*)src + (size_t)b * NN;
    const float2* tar2 = (const float2*)tar + (size_t)b * NN;
    const float*  scb  = scores + (size_t)b * NN;
    const int mOff = q * MQ;

    if (tid < MQ) {
        float2 s = src2[mOff + tid];
        float2 t = tar2[mOff + tid];
        pts[tid] = make_float4(s.x * PATCH, s.y * PATCH, t.x * PATCH, t.y * PATCH);
        sc[tid]  = (s.x != -1.0f) ? scb[mOff + tid] : 0.0f;
    }

    // ---- 4 hypotheses per lane (exact contract-off preamble, unchanged) ----
    const size_t nb = (size_t)b * NN;
    float a00[4], a01[4], a10[4], a11[4], trx[4], trY[4];
#pragma unroll
    for (int h = 0; h < 4; ++h) {
        const int n = g * GH + h * 64 + lane;
        const float sv  = relScale[nb + n];
        const float2 ip = ((const float2*)relInplane)[nb + n];
        float2 s = src2[n], t = tar2[n];
        a00[h] = sv * ip.x;  a01[h] = sv * (-ip.y);
        a10[h] = sv * ip.y;  a11[h] = sv * ip.x;
        const float Px = s.x * PATCH, Py = s.y * PATCH;
        const float Tx = t.x * PATCH, Ty = t.y * PATCH;
        trx[h] = Tx - (a00[h] * Px + a01[h] * Py);
        trY[h] = Ty - (a10[h] * Px + a11[h] * Py);
    }

    __syncthreads();

    float acc[4];
    const int mBeg = wave * ITERS;
    for (int r = 0; r < REPEAT; ++r) {
        acc[0] = 0.0f; acc[1] = 0.0f; acc[2] = 0.0f; acc[3] = 0.0f;
#pragma unroll 4
        for (int mm = 0; mm < ITERS; ++mm) {
            const float4 qp = pts[mBeg + mm];   // same addr across wave -> LDS broadcast
            const float  w  = sc[mBeg + mm];
#pragma unroll
            for (int h = 0; h < 4; ++h) {
                float px = __builtin_fmaf(a00[h], qp.x, __builtin_fmaf(a01[h], qp.y, trx[h]));
                float py = __builtin_fmaf(a10[h], qp.x, __builtin_fmaf(a11[h], qp.y, trY[h]));
                float dx = px - qp.z, dy = py - qp.w;
                float e2 = __builtin_fmaf(dx, dx, dy * dy);
                acc[h] += (e2 <= THRSQ) ? w : 0.0f;
            }
        }
        if (r != REPEAT - 1) {
            // probe-only guards: keep each repeat's acc live (no DCE) and force
            // LDS reloads next repeat (no cross-repeat CSE). Dead code when REPEAT==1.
#pragma unroll
            for (int h = 0; h < 4; ++h) asm volatile("" :: "v"(acc[h]));
            asm volatile("" ::: "memory");
        }
    }
#pragma unroll
    for (int h = 0; h < 4; ++h) partial[wave][h * 64 + lane] = acc[h];
    __syncthreads();

    // ---- combine partials; self point of hyp n lives in this block iff g==q ----
    if (tid < GH) {
        float p = 0.0f;
#pragma unroll
        for (int w = 0; w < WAVES; ++w) p += partial[w][tid];
        if (g == q) p -= sc[tid];          // self e2 ~1e-8, always counted: remove
        score_part[((size_t)q * BB + b) * NN + g * GH + tid] = p;
    }
}

// ---------------- Kernel 2: argmax + M + stable inlier partition ----------------
// grid = BB blocks, 1024 threads (one per point). EXACT arithmetic (contract off).
__global__ __launch_bounds__(1024) void ransac_select_kernel(
    const float* __restrict__ src, const float* __restrict__ tar,
    const float* __restrict__ scores, const float* __restrict__ relScale,
    const float* __restrict__ relInplane,
    const float* __restrict__ score_part, float* __restrict__ out)
{
#pragma clang fp contract(off)
    const int b = blockIdx.x;
    const int tid = threadIdx.x;
    const int lane = tid & 63;
    const int wave = tid >> 6;

    __shared__ float wvalSh[16];
    __shared__ int   widxSh[16];
    __shared__ float prm[6];       // a00 a01 a10 a11 trx trY
    __shared__ int   bestIdxSh;
    __shared__ float bestValSh;
    __shared__ int   wcnt[16], wbase[16];
    __shared__ float osx[NN], osy[NN], otx[NN], oty[NN], osc[NN];

    const size_t gm = (size_t)b * NN + tid;
    const float2 s2 = ((const float2*)src)[gm];
    const float2 t2 = ((const float2*)tar)[gm];
    const float scin = scores[gm];

    float val;
    {
        float p = score_part[(size_t)b * NN + tid]
                + score_part[((size_t)BB + b) * NN + tid]
                + score_part[((size_t)2 * BB + b) * NN + tid]
                + score_part[((size_t)3 * BB + b) * NN + tid];
        val = (s2.x != -1.0f) ? p : -1.0f;
    }
    int idx = tid;

    // ---- argmax, first-index tie-break: wave butterfly then cross-wave ----
    for (int d = 1; d < 64; d <<= 1) {
        float ov = __shfl_xor(val, d);
        int   oi = __shfl_xor(idx, d);
        if (ov > val || (ov == val && oi < idx)) { val = ov; idx = oi; }
    }
    if (lane == 0) { wvalSh[wave] = val; widxSh[wave] = idx; }
    __syncthreads();
    if (tid < 64) {
        float v = (tid < 16) ? wvalSh[tid] : -1e30f;
        int   i = (tid < 16) ? widxSh[tid] : 0x7fffffff;
        for (int d = 1; d < 16; d <<= 1) {
            float ov = __shfl_xor(v, d);
            int   oi = __shfl_xor(i, d);
            if (ov > v || (ov == v && oi < i)) { v = ov; i = oi; }
        }
        if (tid == 0) { bestIdxSh = i; bestValSh = v; }
    }
    __syncthreads();
    const int best = bestIdxSh;

    if (tid == 0) {
        size_t gi = (size_t)b * NN + best;
        float scale = relScale[gi];
        float c  = relInplane[gi * 2];
        float si = relInplane[gi * 2 + 1];
        float a00 = scale * c;
        float a01 = scale * (-si);
        float a10 = scale * si;
        float a11 = scale * c;
        float snx = src[gi * 2] * PATCH, sny = src[gi * 2 + 1] * PATCH;
        float tnx = tar[gi * 2] * PATCH, tny = tar[gi * 2 + 1] * PATCH;
        float trx = tnx - (a00 * snx + a01 * sny);
        float trY = tny - (a10 * snx + a11 * sny);
        prm[0] = a00; prm[1] = a01; prm[2] = a10; prm[3] = a11; prm[4] = trx; prm[5] = trY;

        float* M = out + (size_t)b * 9;
        M[0] = a00; M[1] = a01; M[2] = trx;
        M[3] = a10; M[4] = a11; M[5] = trY;
        M[6] = 0.0f; M[7] = 0.0f; M[8] = 1.0f;
        out[(size_t)BB * 9 + b] = (bestValSh == 0.0f) ? 1.0f : 0.0f;   // failed
    }
    __syncthreads();

    // ---- recompute inlier flag for this thread's point (exact sequence) ----
    float sx = s2.x * PATCH, sy = s2.y * PATCH;
    float tx = t2.x * PATCH, ty = t2.y * PATCH;
    float px = prm[0] * sx + prm[1] * sy + prm[4];
    float py = prm[2] * sx + prm[3] * sy + prm[5];
    float dx = px - tx, dy = py - ty;
    bool flag = (dx * dx + dy * dy <= THRSQ) && (s2.x != -1.0f) && (tid != best);

    // ---- stable exclusive prefix of flags (ballot + popcount + wave scan) ----
    unsigned long long mask = __ballot(flag);
    int posInWave = __popcll(mask & ((1ULL << lane) - 1ULL));
    if (lane == 0) wcnt[wave] = __popcll(mask);
    __syncthreads();
    if (tid < 16) {
        int s = 0;
        for (int i = 0; i < tid; ++i) s += wcnt[i];
        wbase[tid] = s;
    }
    __syncthreads();
    int pos = wbase[wave] + posInWave;

    // ---- stable partition into LDS, then coalesced write ----
    osx[tid] = -1.0f; osy[tid] = -1.0f;
    otx[tid] = -1.0f; oty[tid] = -1.0f;
    osc[tid] = 0.0f;
    __syncthreads();
    if (flag) {
        osx[pos] = s2.x; osy[pos] = s2.y;
        otx[pos] = t2.x; oty[pos] = t2.y;
        osc[pos] = scin;
    }
    __syncthreads();

    const size_t O_SRC = (size_t)BB * 9 + BB;
    const size_t O_TAR = O_SRC + (size_t)BB * NN * 2;
    const size_t O_SC  = O_TAR + (size_t)BB * NN * 2;
    out[O_SRC + gm * 2]     = osx[tid];
    out[O_SRC + gm * 2 + 1] = osy[tid];
    out[O_TAR + gm * 2]     = otx[tid];
    out[O_TAR + gm * 2 + 1] = oty[tid];
    out[O_SC  + gm]         = osc[tid];
}

extern "C" void kernel_launch(void* const* d_in, const int* in_sizes, int n_in,
                              void* d_out, int out_size, void* d_ws, size_t ws_size,
                              hipStream_t stream) {
    const float* src        = (const float*)d_in[0];
    const float* tar        = (const float*)d_in[1];
    const float* scores     = (const float*)d_in[2];
    const float* relScale   = (const float*)d_in[3];
    const float* relInplane = (const float*)d_in[4];
    float* out = (float*)d_out;
    float* score_part = (float*)d_ws;   // 4 * BB * NN floats = 512 KB

    // PROFILING PROBE: 4x-repeated m-loop (~56us) -> surfaces in rocprof top-5
    // with counters. Output fully overwritten by the real kernel below.
    ransac_score_kernel<4><<<BB * 4 * 4, TPB, 0, stream>>>(
        src, tar, scores, relScale, relInplane, score_part);
    // REAL k1: bit-identical to the 19.18us R7 champion.
    ransac_score_kernel<1><<<BB * 4 * 4, TPB, 0, stream>>>(
        src, tar, scores, relScale, relInplane, score_part);
    ransac_select_kernel<<<BB, NN, 0, stream>>>(
        src, tar, scores, relScale, relInplane, score_part, out);
}

// Round 14
// 19.619 us; speedup vs baseline: 2.4307x; 2.4307x over previous
//
#include <hip/hip_runtime.h>

constexpr int BB = 32;
constexpr int NN = 1024;
constexpr int TPB = 512;            // 8 waves
constexpr int WAVES = 8;
constexpr int GH = 256;             // hypotheses per block (4 per lane, contiguous)
constexpr int MQ = 256;             // m-points per block (quarter of batch)
constexpr int ITERS = MQ / WAVES;   // 32
#define PATCH 14.0f
#define THRSQ 25.0f   // PIXEL_THRESHOLD^2 ; sqrt(x)<=5 <=> x<=25 for correctly-rounded sqrt

// ---------------- Kernel 1: score every hypothesis (CODE-SIZE-MINIMIZED) ----------------
// Same math as the 19.18us R7 champion, bit-identical score_part output.
// Changes are code-size only (cold-icache theory): rolled m-loop (unroll 1),
// lane owns 4 CONTIGUOUS hyps (4*lane..4*lane+3) so the preamble is 7 vector
// loads, and the partial write is a single ds_write_b128.
__global__ __launch_bounds__(TPB, 3) void ransac_score_kernel(
    const float* __restrict__ src, const float* __restrict__ tar,
    const float* __restrict__ scores, const float* __restrict__ relScale,
    const float* __restrict__ relInplane, float* __restrict__ score_part)
{
#pragma clang fp contract(off)
    const int bid  = blockIdx.x;
    const int q    = bid & 3;
    const int g    = (bid >> 2) & 3;
    const int b    = bid >> 4;
    const int tid  = threadIdx.x;
    const int wave = tid >> 6;
    const int lane = tid & 63;

    __shared__ float4 pts[MQ];              // (sx,sy,tx,ty)*PATCH for this quarter
    __shared__ float  sc[MQ];               // score, zeroed for invalid points
    __shared__ float4 partial4[WAVES][64];  // [w][lane] = accs of hyps 4*lane..4*lane+3
                                            // (linearly identical to [w][256] float)

    const float2* src2 = (const float2*)src + (size_t)b * NN;
    const float2* tar2 = (const float2*)tar + (size_t)b * NN;
    const float*  scb  = scores + (size_t)b * NN;
    const int mOff = q * MQ;

    if (tid < MQ) {
        float2 s = src2[mOff + tid];
        float2 t = tar2[mOff + tid];
        pts[tid] = make_float4(s.x * PATCH, s.y * PATCH, t.x * PATCH, t.y * PATCH);
        sc[tid]  = (s.x != -1.0f) ? scb[mOff + tid] : 0.0f;
    }

    // ---- 4 contiguous hyps per lane: 7 vector loads, exact same per-hyp math ----
    const size_t nb = (size_t)b * NN;
    const float4  sv4 = ((const float4*)(relScale + nb + g * GH))[lane];
    const float4* ip4 = (const float4*)((const float2*)relInplane + nb + g * GH);
    const float4  ipA = ip4[2 * lane], ipB = ip4[2 * lane + 1];
    const float4* s4  = (const float4*)(src2 + g * GH);
    const float4  sA  = s4[2 * lane],  sB  = s4[2 * lane + 1];
    const float4* t4  = (const float4*)(tar2 + g * GH);
    const float4  tA  = t4[2 * lane],  tB  = t4[2 * lane + 1];

    float a00[4], a01[4], a10[4], a11[4], trx[4], trY[4];
    {
        const float sv[4] = {sv4.x, sv4.y, sv4.z, sv4.w};
        const float ic[4] = {ipA.x, ipA.z, ipB.x, ipB.z};
        const float is[4] = {ipA.y, ipA.w, ipB.y, ipB.w};
        const float Sx[4] = {sA.x, sA.z, sB.x, sB.z};
        const float Sy[4] = {sA.y, sA.w, sB.y, sB.w};
        const float Tx[4] = {tA.x, tA.z, tB.x, tB.z};
        const float Ty[4] = {tA.y, tA.w, tB.y, tB.w};
#pragma unroll
        for (int h = 0; h < 4; ++h) {
            a00[h] = sv[h] * ic[h];  a01[h] = sv[h] * (-is[h]);
            a10[h] = sv[h] * is[h];  a11[h] = sv[h] * ic[h];
            const float Px = Sx[h] * PATCH, Py = Sy[h] * PATCH;
            const float TxP = Tx[h] * PATCH, TyP = Ty[h] * PATCH;
            trx[h] = TxP - (a00[h] * Px + a01[h] * Py);
            trY[h] = TyP - (a10[h] * Px + a11[h] * Py);
        }
    }

    __syncthreads();

    float acc[4] = {0.0f, 0.0f, 0.0f, 0.0f};
    const int mBeg = wave * ITERS;
#pragma unroll 1
    for (int mm = 0; mm < ITERS; ++mm) {
        const float4 qp = pts[mBeg + mm];   // same addr across wave -> LDS broadcast
        const float  w  = sc[mBeg + mm];
#pragma unroll
        for (int h = 0; h < 4; ++h) {
            float px = __builtin_fmaf(a00[h], qp.x, __builtin_fmaf(a01[h], qp.y, trx[h]));
            float py = __builtin_fmaf(a10[h], qp.x, __builtin_fmaf(a11[h], qp.y, trY[h]));
            float dx = px - qp.z, dy = py - qp.w;
            float e2 = __builtin_fmaf(dx, dx, dy * dy);
            acc[h] += (e2 <= THRSQ) ? w : 0.0f;
        }
    }
    partial4[wave][lane] = make_float4(acc[0], acc[1], acc[2], acc[3]);
    __syncthreads();

    // ---- combine; float view of partial4 is [w][256]: element tid = hyp g*GH+tid ----
    if (tid < GH) {
        const float* pl = (const float*)partial4;
        float p = 0.0f;
#pragma unroll
        for (int w = 0; w < WAVES; ++w) p += pl[w * GH + tid];
        if (g == q) p -= sc[tid];          // self e2 ~1e-8, always counted: remove
        score_part[((size_t)q * BB + b) * NN + g * GH + tid] = p;
    }
}

// ---------------- Kernel 2: argmax + M + stable inlier partition ----------------
// grid = BB blocks, 1024 threads (one per point). EXACT arithmetic (contract off).
__global__ __launch_bounds__(1024) void ransac_select_kernel(
    const float* __restrict__ src, const float* __restrict__ tar,
    const float* __restrict__ scores, const float* __restrict__ relScale,
    const float* __restrict__ relInplane,
    const float* __restrict__ score_part, float* __restrict__ out)
{
#pragma clang fp contract(off)
    const int b = blockIdx.x;
    const int tid = threadIdx.x;
    const int lane = tid & 63;
    const int wave = tid >> 6;

    __shared__ float wvalSh[16];
    __shared__ int   widxSh[16];
    __shared__ float prm[6];       // a00 a01 a10 a11 trx trY
    __shared__ int   bestIdxSh;
    __shared__ float bestValSh;
    __shared__ int   wcnt[16], wbase[16];
    __shared__ float osx[NN], osy[NN], otx[NN], oty[NN], osc[NN];

    const size_t gm = (size_t)b * NN + tid;
    const float2 s2 = ((const float2*)src)[gm];
    const float2 t2 = ((const float2*)tar)[gm];
    const float scin = scores[gm];

    float val;
    {
        float p = score_part[(size_t)b * NN + tid]
                + score_part[((size_t)BB + b) * NN + tid]
                + score_part[((size_t)2 * BB + b) * NN + tid]
                + score_part[((size_t)3 * BB + b) * NN + tid];
        val = (s2.x != -1.0f) ? p : -1.0f;
    }
    int idx = tid;

    // ---- argmax, first-index tie-break: wave butterfly then cross-wave ----
    for (int d = 1; d < 64; d <<= 1) {
        float ov = __shfl_xor(val, d);
        int   oi = __shfl_xor(idx, d);
        if (ov > val || (ov == val && oi < idx)) { val = ov; idx = oi; }
    }
    if (lane == 0) { wvalSh[wave] = val; widxSh[wave] = idx; }
    __syncthreads();
    if (tid < 64) {
        float v = (tid < 16) ? wvalSh[tid] : -1e30f;
        int   i = (tid < 16) ? widxSh[tid] : 0x7fffffff;
        for (int d = 1; d < 16; d <<= 1) {
            float ov = __shfl_xor(v, d);
            int   oi = __shfl_xor(i, d);
            if (ov > v || (ov == v && oi < i)) { v = ov; i = oi; }
        }
        if (tid == 0) { bestIdxSh = i; bestValSh = v; }
    }
    __syncthreads();
    const int best = bestIdxSh;

    if (tid == 0) {
        size_t gi = (size_t)b * NN + best;
        float scale = relScale[gi];
        float c  = relInplane[gi * 2];
        float si = relInplane[gi * 2 + 1];
        float a00 = scale * c;
        float a01 = scale * (-si);
        float a10 = scale * si;
        float a11 = scale * c;
        float snx = src[gi * 2] * PATCH, sny = src[gi * 2 + 1] * PATCH;
        float tnx = tar[gi * 2] * PATCH, tny = tar[gi * 2 + 1] * PATCH;
        float trx = tnx - (a00 * snx + a01 * sny);
        float trY = tny - (a10 * snx + a11 * sny);
        prm[0] = a00; prm[1] = a01; prm[2] = a10; prm[3] = a11; prm[4] = trx; prm[5] = trY;

        float* M = out + (size_t)b * 9;
        M[0] = a00; M[1] = a01; M[2] = trx;
        M[3] = a10; M[4] = a11; M[5] = trY;
        M[6] = 0.0f; M[7] = 0.0f; M[8] = 1.0f;
        out[(size_t)BB * 9 + b] = (bestValSh == 0.0f) ? 1.0f : 0.0f;   // failed
    }
    __syncthreads();

    // ---- recompute inlier flag for this thread's point (exact sequence) ----
    float sx = s2.x * PATCH, sy = s2.y * PATCH;
    float tx = t2.x * PATCH, ty = t2.y * PATCH;
    float px = prm[0] * sx + prm[1] * sy + prm[4];
    float py = prm[2] * sx + prm[3] * sy + prm[5];
    float dx = px - tx, dy = py - ty;
    bool flag = (dx * dx + dy * dy <= THRSQ) && (s2.x != -1.0f) && (tid != best);

    // ---- stable exclusive prefix of flags (ballot + popcount + wave scan) ----
    unsigned long long mask = __ballot(flag);
    int posInWave = __popcll(mask & ((1ULL << lane) - 1ULL));
    if (lane == 0) wcnt[wave] = __popcll(mask);
    __syncthreads();
    if (tid < 16) {
        int s = 0;
        for (int i = 0; i < tid; ++i) s += wcnt[i];
        wbase[tid] = s;
    }
    __syncthreads();
    int pos = wbase[wave] + posInWave;

    // ---- stable partition into LDS, then coalesced write ----
    osx[tid] = -1.0f; osy[tid] = -1.0f;
    otx[tid] = -1.0f; oty[tid] = -1.0f;
    osc[tid] = 0.0f;
    __syncthreads();
    if (flag) {
        osx[pos] = s2.x; osy[pos] = s2.y;
        otx[pos] = t2.x; oty[pos] = t2.y;
        osc[pos] = scin;
    }
    __syncthreads();

    const size_t O_SRC = (size_t)BB * 9 + BB;
    const size_t O_TAR = O_SRC + (size_t)BB * NN * 2;
    const size_t O_SC  = O_TAR + (size_t)BB * NN * 2;
    out[O_SRC + gm * 2]     = osx[tid];
    out[O_SRC + gm * 2 + 1] = osy[tid];
    out[O_TAR + gm * 2]     = otx[tid];
    out[O_TAR + gm * 2 + 1] = oty[tid];
    out[O_SC  + gm]         = osc[tid];
}

extern "C" void kernel_launch(void* const* d_in, const int* in_sizes, int n_in,
                              void* d_out, int out_size, void* d_ws, size_t ws_size,
                              hipStream_t stream) {
    const float* src        = (const float*)d_in[0];
    const float* tar        = (const float*)d_in[1];
    const float* scores     = (const float*)d_in[2];
    const float* relScale   = (const float*)d_in[3];
    const float* relInplane = (const float*)d_in[4];
    float* out = (float*)d_out;
    float* score_part = (float*)d_ws;   // 4 * BB * NN floats = 512 KB

    ransac_score_kernel<<<BB * 4 * 4, TPB, 0, stream>>>(
        src, tar, scores, relScale, relInplane, score_part);
    ransac_select_kernel<<<BB, NN, 0, stream>>>(
        src, tar, scores, relScale, relInplane, score_part, out);
}